// Round 10
// baseline (223.659 us; speedup 1.0000x reference)
//
#include <hip/hip_runtime.h>
#include <hip/hip_bf16.h>
#include <math.h>

#define NH 16
#define S_LEN 1024
#define DK 64
#define D_MODEL 1024
#define HSZ 8388608          // B*NH*S*DK elements per q/k/v buffer

typedef __attribute__((ext_vector_type(8))) short bf16x8;
typedef __attribute__((ext_vector_type(4))) float f32x4;
typedef unsigned short USH;

#define EXPSCALE 0.1803368801111204f   // 0.125 * log2(e)

__device__ __forceinline__ float fast_exp2(float x) {
    return __builtin_amdgcn_exp2f(x);
}

__device__ __forceinline__ short f2b(float x) {
    union { __hip_bfloat16 h; short s; } u;
    u.h = __float2bfloat16(x);
    return u.s;
}
__device__ __forceinline__ float b2f(USH u) {
    union { unsigned i; float f; } x;
    x.i = (unsigned)u << 16;
    return x.f;
}

__device__ __forceinline__ void gload16(const void* src, void* lds) {
    __builtin_amdgcn_global_load_lds(
        (const __attribute__((address_space(1))) void*)src,
        (__attribute__((address_space(3))) void*)lds,
        16, 0, 0);
}

// ---------------------------------------------------------------------------
// fp32 -> bf16 conversion (exact-grid, 8 elems/thread)
// ---------------------------------------------------------------------------
__global__ __launch_bounds__(256)
void conv_bf16_kernel(const float* __restrict__ in, USH* __restrict__ out) {
    const int i = (blockIdx.x * 256 + threadIdx.x) * 8;
    const float4 a = *(const float4*)&in[i];
    const float4 b = *(const float4*)&in[i + 4];
    ushort4 o0, o1;
    o0.x = (USH)f2b(a.x); o0.y = (USH)f2b(a.y); o0.z = (USH)f2b(a.z); o0.w = (USH)f2b(a.w);
    o1.x = (USH)f2b(b.x); o1.y = (USH)f2b(b.y); o1.z = (USH)f2b(b.z); o1.w = (USH)f2b(b.w);
    *(ushort4*)&out[i] = o0;
    *(ushort4*)&out[i + 4] = o1;
}

// ---------------------------------------------------------------------------
// Transpose + convert: in [R][C] fp32 -> out [C][R] bf16. 64x64 tiles.
// ---------------------------------------------------------------------------
__global__ __launch_bounds__(256)
void transp_bf16_kernel(const float* __restrict__ in, USH* __restrict__ out,
                        int R, int C) {
    __shared__ USH Ts[64][65];
    const int r0 = blockIdx.y * 64, c0 = blockIdx.x * 64;
    const int tr = threadIdx.x >> 4;
    const int tc4 = (threadIdx.x & 15) * 4;
    #pragma unroll
    for (int ph = 0; ph < 4; ++ph) {
        const int r = ph * 16 + tr;
        const float4 v = *(const float4*)&in[(size_t)(r0 + r) * C + c0 + tc4];
        Ts[tc4 + 0][r] = (USH)f2b(v.x);
        Ts[tc4 + 1][r] = (USH)f2b(v.y);
        Ts[tc4 + 2][r] = (USH)f2b(v.z);
        Ts[tc4 + 3][r] = (USH)f2b(v.w);
    }
    __syncthreads();
    #pragma unroll
    for (int ph = 0; ph < 4; ++ph) {
        const int cc = ph * 16 + tr;
        ushort4 o;
        o.x = Ts[cc][tc4 + 0]; o.y = Ts[cc][tc4 + 1];
        o.z = Ts[cc][tc4 + 2]; o.w = Ts[cc][tc4 + 3];
        *(ushort4*)&out[(size_t)(c0 + cc) * R + r0 + tc4] = o;
    }
}

// ---------------------------------------------------------------------------
// bf16 MFMA GEMM (m97 structure) — q/k/v written bf16 when QKV=1.
// V is written DIRECTLY TRANSPOSED per head: vtg[bh][d][s].
// ---------------------------------------------------------------------------
template<int QKV>
__global__ __launch_bounds__(256)
void mfma_gemm_kernel(const USH* __restrict__ A, const USH* __restrict__ Bt,
                      const float* __restrict__ bias,
                      float* __restrict__ Cf, USH* __restrict__ Cq,
                      USH* __restrict__ Ck, USH* __restrict__ Cv,
                      int M, int N, int K) {
    __shared__ __align__(16) USH As[128 * 32];
    __shared__ __align__(16) USH Bs[128 * 32];
    const int t = threadIdx.x;
    const int w = t >> 6, lane = t & 63, g = lane >> 4, c = lane & 15;
    const int wm = w >> 1, wn = w & 1;
    const int bm0 = blockIdx.y * 128, bn0 = blockIdx.x * 128;

    const int sk = ((t & 3) ^ ((t >> 3) & 3)) * 8;
    const USH* pa0 = A + (size_t)(bm0 + (t >> 2)) * K + sk;
    const USH* pa1 = pa0 + (size_t)64 * K;
    const USH* pb0 = Bt + (size_t)(bn0 + (t >> 2)) * K + sk;
    const USH* pb1 = pb0 + (size_t)64 * K;
    USH* ldsA0 = &As[(t & ~63) * 8];
    USH* ldsA1 = ldsA0 + 2048;
    USH* ldsB0 = &Bs[(t & ~63) * 8];
    USH* ldsB1 = ldsB0 + 2048;

    unsigned aoff[4], boff[4];
    #pragma unroll
    for (int i = 0; i < 4; ++i) {
        const int r = wm * 64 + i * 16 + c;
        aoff[i] = ((unsigned)(r * 64 + g * 16)) ^ ((((unsigned)r >> 1) & 3) << 4);
        const int n = wn * 64 + i * 16 + c;
        boff[i] = ((unsigned)(n * 64 + g * 16)) ^ ((((unsigned)n >> 1) & 3) << 4);
    }

    f32x4 acc[4][4];
    #pragma unroll
    for (int i = 0; i < 4; ++i)
        #pragma unroll
        for (int j = 0; j < 4; ++j) acc[i][j] = (f32x4)0.f;

    for (int k0 = 0; k0 < K; k0 += 32) {
        gload16(pa0 + k0, ldsA0);
        gload16(pa1 + k0, ldsA1);
        gload16(pb0 + k0, ldsB0);
        gload16(pb1 + k0, ldsB1);
        __syncthreads();

        bf16x8 af[4], bfr[4];
        #pragma unroll
        for (int i = 0; i < 4; ++i) af[i] = *(const bf16x8*)((const char*)As + aoff[i]);
        #pragma unroll
        for (int j = 0; j < 4; ++j) bfr[j] = *(const bf16x8*)((const char*)Bs + boff[j]);
        #pragma unroll
        for (int i = 0; i < 4; ++i)
            #pragma unroll
            for (int j = 0; j < 4; ++j)
                acc[i][j] = __builtin_amdgcn_mfma_f32_16x16x32_bf16(
                    af[i], bfr[j], acc[i][j], 0, 0, 0);
        __syncthreads();
    }

    #pragma unroll
    for (int i = 0; i < 4; ++i) {
        #pragma unroll
        for (int reg = 0; reg < 4; ++reg) {
            const int m = bm0 + wm * 64 + i * 16 + g * 4 + reg;
            #pragma unroll
            for (int j = 0; j < 4; ++j) {
                const int n = bn0 + wn * 64 + j * 16 + c;
                const float v = acc[i][j][reg] + bias[n];
                if (QKV) {
                    const int which = n >> 10;
                    const int h = (n & 1023) >> 6, d = n & 63;
                    const int b = m >> 10, s = m & 1023;
                    if (which == 0) {
                        Cq[(((size_t)(b * NH + h)) * S_LEN + s) * DK + d] = (USH)f2b(v);
                    } else if (which == 1) {
                        Ck[(((size_t)(b * NH + h)) * S_LEN + s) * DK + d] = (USH)f2b(v);
                    } else {
                        // transposed: vtg[bh][d][s]
                        Cv[(((size_t)(b * NH + h)) * DK + d) * S_LEN + s] = (USH)f2b(v);
                    }
                } else {
                    Cf[(size_t)m * N + n] = v;
                }
            }
        }
    }
}

// ---------------------------------------------------------------------------
// MFMA flash attention: 8 waves x 128 q-rows per block, KVBLK=64, dbuf async
// staging. Fixed-shift softmax; per-lane partial sums reduced in epilogue.
// LPT ordering: heavy blocks (large ib) dispatch FIRST.
// ---------------------------------------------------------------------------
__global__ __launch_bounds__(512, 4)
void attn_mfma_kernel(const USH* __restrict__ qb,
                      const USH* __restrict__ kbuf,
                      const USH* __restrict__ vtg,
                      const float* __restrict__ lut_k,
                      const float* __restrict__ lut_v,
                      USH* __restrict__ ao) {
    const int bid = blockIdx.x;
    const int logical = (bid & 7) * 128 + (bid >> 3);   // XCD-contiguous bh
    const int ib = 7 - (logical & 7);                   // LPT: big ib first
    const int bh = logical >> 3;
    const int b = bh >> 4, h = bh & 15;
    const int i0 = ib * 128;
    const int t = threadIdx.x;
    const int w = t >> 6;          // 0..7
    const int lane = t & 63;
    const int g = lane >> 4;
    const int c = lane & 15;

    __shared__ __align__(16) char smem[64640];
    char* pb    = smem + 32768;              // P buffers (main loop)
    char* qsb   = smem + 32768;              // phase0 alias: q [128][64] swz
    char* lutkb = smem + 56448;              // phase0 alias of tapss
    USH* qrelb  = (USH*)(smem + 49152);      // [128][20] bf16
    USH* lvfb   = (USH*)(smem + 54272);      // [17][64] bf16
    float* tapss = (float*)(smem + 56448);   // [128][16] p values

    const USH* qp  = qb   + (size_t)bh * (S_LEN * DK);
    const USH* kp  = kbuf + (size_t)bh * (S_LEN * DK);
    const USH* vtp = vtg  + (size_t)bh * (S_LEN * DK);  // [d=64][s=1024]

    // async stage of one 64x64 K tile + V^T tile (512 thr = 1 gload16 each)
    auto stage = [&](int j0, int koff, int voff) {
        const int o = t * 16;
        const int row = o >> 7;
        const int chunk = (o >> 4) & 7;
        const int sc = (chunk ^ (row & 7)) * 8;
        gload16(kp + (size_t)(j0 + row) * DK + sc, smem + koff + o);
        gload16(vtp + (size_t)row * S_LEN + j0 + sc, smem + voff + o);
    };

    // ---- phase 0: issue tile-0 loads; stage q (bf16, swizzled) + LUTs ----
    stage(0, 0, 16384);
    for (int f = t; f < 2048; f += 512) {
        const int row = f >> 4, c4 = (f & 15) * 4;
        unsigned byte = ((unsigned)(row * 128 + c4 * 2)) ^ (((unsigned)row & 7) << 4);
        *(ushort4*)(qsb + byte) = *(const ushort4*)&qp[(size_t)(i0 + row) * DK + c4];
    }
    // lut_k -> bf16 LDS [32][64], rows 17..31 zero, swizzled
    for (int e = t; e < 32 * 64; e += 512) {
        const int row = e >> 6, d = e & 63;
        const USH v = (row < 17) ? (USH)f2b(lut_k[row * 64 + d]) : (USH)0;
        unsigned byte = ((unsigned)(row * 128 + d * 2)) ^ (((unsigned)row & 7) << 4);
        *(USH*)(lutkb + byte) = v;
    }
    for (int e = t; e < 17 * 64; e += 512)
        lvfb[e] = (USH)f2b(lut_v[e]);
    __syncthreads();   // drains tile-0 gloads too

    // Q fragments straight from swizzled bf16 LDS (wave w owns rows w*16..+15)
    bf16x8 qa[2];
    {
        const int row = w * 16 + c;
        #pragma unroll
        for (int kh = 0; kh < 2; ++kh) {
            unsigned byte = ((unsigned)(row * 128 + kh * 64 + g * 16))
                          ^ (((unsigned)row & 7) << 4);
            qa[kh] = *(const bf16x8*)(qsb + byte);
        }
    }

    // qrel via MFMA: lut_k rows as 17 virtual keys (2 col sub-tiles)
    {
        f32x4 qr[2];
        qr[0] = (f32x4)0.f; qr[1] = (f32x4)0.f;
        #pragma unroll
        for (int sub2 = 0; sub2 < 2; ++sub2) {
            const int tap = sub2 * 16 + c;
            #pragma unroll
            for (int kh = 0; kh < 2; ++kh) {
                unsigned byte = ((unsigned)(tap * 128 + kh * 64 + g * 16))
                              ^ (((unsigned)tap & 7) << 4);
                bf16x8 lb = *(const bf16x8*)(lutkb + byte);
                qr[sub2] = __builtin_amdgcn_mfma_f32_16x16x32_bf16(
                    qa[kh], lb, qr[sub2], 0, 0, 0);
            }
        }
        #pragma unroll
        for (int sub2 = 0; sub2 < 2; ++sub2) {
            const int tap = sub2 * 16 + c;
            if (tap < 17) {
                #pragma unroll
                for (int r = 0; r < 4; ++r)
                    qrelb[(w * 16 + g * 4 + r) * 20 + tap] = (USH)f2b(qr[sub2][r]);
            }
        }
    }
    __syncthreads();   // qsb/lutkb dead; qrelb ready; pb/tapss free

    // hoist tap-0 qrel (pre-scaled by EXPSCALE) for interior tiles
    float qrel0s[4];
    #pragma unroll
    for (int r = 0; r < 4; ++r)
        qrel0s[r] = b2f(qrelb[(w * 16 + g * 4 + r) * 20]) * EXPSCALE;

    f32x4 acc[4];
    #pragma unroll
    for (int dt = 0; dt < 4; ++dt) acc[dt] = (f32x4)0.f;
    float l_r[4];   // per-lane PARTIAL row sums (reduced in epilogue)
    #pragma unroll
    for (int r = 0; r < 4; ++r) l_r[r] = 0.f;

    const int NT = 2 * ib + 2;
    for (int tile = 0; tile < NT; ++tile) {
        const int cur = tile & 1;
        if (tile + 1 < NT)
            stage((tile + 1) << 6, cur ? 0 : 8192, cur ? 16384 : 24576);
        const char* ktb = smem + (cur ? 8192 : 0);
        const char* vtb = smem + (cur ? 24576 : 16384);

        // ---- QK^T ----
        float p[4][4];
        __builtin_amdgcn_s_setprio(1);
        f32x4 s[4];
        #pragma unroll
        for (int sub = 0; sub < 4; ++sub) {
            s[sub] = (f32x4)0.f;
            const int krow = sub * 16 + c;
            #pragma unroll
            for (int kh = 0; kh < 2; ++kh) {
                unsigned byte = ((unsigned)krow << 7) + ((unsigned)kh << 6) + ((unsigned)g << 4);
                byte ^= (unsigned)(krow & 7) << 4;
                bf16x8 kb = *(const bf16x8*)(ktb + byte);
                s[sub] = __builtin_amdgcn_mfma_f32_16x16x32_bf16(qa[kh], kb, s[sub], 0, 0, 0);
            }
        }
        __builtin_amdgcn_s_setprio(0);

        if (tile < NT - 3) {
            // ---- interior fast path: dj <= -65 -> tap index 0 everywhere ----
            #pragma unroll
            for (int sub = 0; sub < 4; ++sub)
                #pragma unroll
                for (int r = 0; r < 4; ++r)
                    p[sub][r] = fast_exp2(s[sub][r] * EXPSCALE + qrel0s[r]);
        } else {
            // ---- boundary: clamped tap lookup + causal mask + tap capture ----
            #pragma unroll
            for (int sub = 0; sub < 4; ++sub) {
                const int dbase = tile * 64 + (sub * 16 + c) - i0 - (w * 16 + g * 4);
                #pragma unroll
                for (int r = 0; r < 4; ++r) {
                    const int dj = dbase - r;
                    int t17 = dj + 16;
                    t17 = t17 < 0 ? 0 : (t17 > 16 ? 16 : t17);
                    const int il = w * 16 + g * 4 + r;
                    float pv = fast_exp2((s[sub][r] + b2f(qrelb[il * 20 + t17])) * EXPSCALE);
                    if (dj > 0) pv = 0.f;
                    p[sub][r] = pv;
                    if (dj >= -15 && dj <= 0)
                        tapss[il * 16 + dj + 15] = pv;
                }
            }
        }

        // ---- accumulate per-lane partial row sums (no cross-lane ops) ----
        #pragma unroll
        for (int r = 0; r < 4; ++r)
            l_r[r] += (p[0][r] + p[1][r]) + (p[2][r] + p[3][r]);

        // ---- P -> per-wave LDS (bf16, swizzled) ----
        char* pw = pb + w * 2048;
        #pragma unroll
        for (int sub = 0; sub < 4; ++sub)
            #pragma unroll
            for (int r = 0; r < 4; ++r) {
                const int row = g * 4 + r;
                unsigned byte = ((unsigned)row << 7) + (((unsigned)(sub * 16 + c)) << 1);
                byte ^= (unsigned)(row & 7) << 4;
                *(short*)(pw + byte) = f2b(p[sub][r]);
            }

        // ---- PV ----
        bf16x8 pa[2];
        #pragma unroll
        for (int jh = 0; jh < 2; ++jh) {
            unsigned byte = ((unsigned)c << 7) + ((unsigned)jh << 6) + ((unsigned)g << 4);
            byte ^= (unsigned)(c & 7) << 4;
            pa[jh] = *(const bf16x8*)(pw + byte);
        }
        __builtin_amdgcn_s_setprio(1);
        #pragma unroll
        for (int dt = 0; dt < 4; ++dt) {
            const int d = dt * 16 + c;
            #pragma unroll
            for (int jh = 0; jh < 2; ++jh) {
                unsigned byte = ((unsigned)d << 7) + ((unsigned)jh << 6) + ((unsigned)g << 4);
                byte ^= (unsigned)(d & 7) << 4;
                bf16x8 vb = *(const bf16x8*)(vtb + byte);
                acc[dt] = __builtin_amdgcn_mfma_f32_16x16x32_bf16(pa[jh], vb, acc[dt], 0, 0, 0);
            }
        }
        __builtin_amdgcn_s_setprio(0);
        __syncthreads();
    }

    // ---- epilogue: reduce row sums, taps + bin-0 residual, write ----
    const int rbase = w * 16 + g * 4;
    #pragma unroll
    for (int r = 0; r < 4; ++r) {
        float lsum = l_r[r];
        #pragma unroll
        for (int msk = 1; msk < 16; msk <<= 1)
            lsum += __shfl_xor(lsum, msk);
        const int il = rbase + r;
        float c0 = lsum;
        float tp[16];
        #pragma unroll
        for (int tap = 0; tap < 16; ++tap) {
            const int jg = i0 + il + tap - 15;
            const float pv = (jg >= 0) ? tapss[il * 16 + tap] : 0.f;
            tp[tap] = pv;
            c0 -= pv;
        }
        const float invl = 1.f / lsum;
        #pragma unroll
        for (int dt = 0; dt < 4; ++dt) {
            const int d = dt * 16 + c;
            float o = acc[dt][r] + c0 * b2f(lvfb[d]);
            #pragma unroll
            for (int tap = 0; tap < 16; ++tap)
                o += tp[tap] * b2f(lvfb[(tap + 1) * 64 + d]);
            o *= invl;
            ao[((size_t)b * S_LEN + (i0 + il)) * D_MODEL + h * DK + d] = (USH)f2b(o);
        }
    }
}

// ---------------------------------------------------------------------------
extern "C" void kernel_launch(void* const* d_in, const int* in_sizes, int n_in,
                              void* d_out, int out_size, void* d_ws, size_t ws_size,
                              hipStream_t stream) {
    const float* x      = (const float*)d_in[0];
    const float* W_attn = (const float*)d_in[1];
    const float* b_attn = (const float*)d_in[2];
    const float* W_proj = (const float*)d_in[3];
    const float* b_proj = (const float*)d_in[4];
    const float* lut_k  = (const float*)d_in[5];
    const float* lut_v  = (const float*)d_in[6];
    float* out = (float*)d_out;

    // workspace layout (all USH)
    USH* qb    = (USH*)d_ws;            // 8M
    USH* kb    = qb + HSZ;              // 8M
    USH* vb    = kb + HSZ;              // 8M (unused this round)
    USH* vtg   = vb + HSZ;              // 8M (per-head transposed V, written by GEMM)
    USH* aob   = vtg + HSZ;             // 8M
    USH* xb    = aob + HSZ;             // 8M
    USH* watt  = xb + HSZ;              // 3M
    USH* wproj = watt + 3145728;        // 1M

    // 0) conversions
    conv_bf16_kernel<<<HSZ / (256 * 8), 256, 0, stream>>>(x, xb);
    transp_bf16_kernel<<<dim3(3072 / 64, 1024 / 64), 256, 0, stream>>>(
        W_attn, watt, 1024, 3072);
    transp_bf16_kernel<<<dim3(1024 / 64, 1024 / 64), 256, 0, stream>>>(
        W_proj, wproj, 1024, 1024);

    // 1) QKV projection (bf16 MFMA); V written directly transposed
    mfma_gemm_kernel<1><<<dim3(3072 / 128, 8192 / 128), 256, 0, stream>>>(
        xb, watt, b_attn, nullptr, qb, kb, vtg, 8192, 3072, 1024);

    // 2) attention (8 waves x 128 q-rows per block, LPT ordering)
    attn_mfma_kernel<<<1024, 512, 0, stream>>>(qb, kb, vtg, lut_k, lut_v, aob);

    // 3) output projection (bf16 MFMA)
    mfma_gemm_kernel<0><<<dim3(1024 / 128, 8192 / 128), 256, 0, stream>>>(
        aob, wproj, b_proj, out, nullptr, nullptr, nullptr, 8192, 1024, 1024);
}

// Round 11
// 206.248 us; speedup vs baseline: 1.0844x; 1.0844x over previous
//
#include <hip/hip_runtime.h>
#include <hip/hip_bf16.h>
#include <math.h>

#define NH 16
#define S_LEN 1024
#define DK 64
#define D_MODEL 1024
#define HSZ 8388608          // B*NH*S*DK elements per q/k/v buffer

typedef __attribute__((ext_vector_type(8))) short bf16x8;
typedef __attribute__((ext_vector_type(4))) float f32x4;
typedef unsigned short USH;

#define EXPSCALE 0.1803368801111204f   // 0.125 * log2(e)

__device__ __forceinline__ float fast_exp2(float x) {
    return __builtin_amdgcn_exp2f(x);
}

__device__ __forceinline__ short f2b(float x) {
    union { __hip_bfloat16 h; short s; } u;
    u.h = __float2bfloat16(x);
    return u.s;
}
__device__ __forceinline__ float b2f(USH u) {
    union { unsigned i; float f; } x;
    x.i = (unsigned)u << 16;
    return x.f;
}

__device__ __forceinline__ void gload16(const void* src, void* lds) {
    __builtin_amdgcn_global_load_lds(
        (const __attribute__((address_space(1))) void*)src,
        (__attribute__((address_space(3))) void*)lds,
        16, 0, 0);
}

// ---------------------------------------------------------------------------
// fp32 -> bf16 conversion (exact-grid, 8 elems/thread)
// ---------------------------------------------------------------------------
__global__ __launch_bounds__(256)
void conv_bf16_kernel(const float* __restrict__ in, USH* __restrict__ out) {
    const int i = (blockIdx.x * 256 + threadIdx.x) * 8;
    const float4 a = *(const float4*)&in[i];
    const float4 b = *(const float4*)&in[i + 4];
    ushort4 o0, o1;
    o0.x = (USH)f2b(a.x); o0.y = (USH)f2b(a.y); o0.z = (USH)f2b(a.z); o0.w = (USH)f2b(a.w);
    o1.x = (USH)f2b(b.x); o1.y = (USH)f2b(b.y); o1.z = (USH)f2b(b.z); o1.w = (USH)f2b(b.w);
    *(ushort4*)&out[i] = o0;
    *(ushort4*)&out[i + 4] = o1;
}

// ---------------------------------------------------------------------------
// Transpose + convert: in [R][C] fp32 -> out [C][R] bf16. 64x64 tiles.
// ---------------------------------------------------------------------------
__global__ __launch_bounds__(256)
void transp_bf16_kernel(const float* __restrict__ in, USH* __restrict__ out,
                        int R, int C) {
    __shared__ USH Ts[64][65];
    const int r0 = blockIdx.y * 64, c0 = blockIdx.x * 64;
    const int tr = threadIdx.x >> 4;
    const int tc4 = (threadIdx.x & 15) * 4;
    #pragma unroll
    for (int ph = 0; ph < 4; ++ph) {
        const int r = ph * 16 + tr;
        const float4 v = *(const float4*)&in[(size_t)(r0 + r) * C + c0 + tc4];
        Ts[tc4 + 0][r] = (USH)f2b(v.x);
        Ts[tc4 + 1][r] = (USH)f2b(v.y);
        Ts[tc4 + 2][r] = (USH)f2b(v.z);
        Ts[tc4 + 3][r] = (USH)f2b(v.w);
    }
    __syncthreads();
    #pragma unroll
    for (int ph = 0; ph < 4; ++ph) {
        const int cc = ph * 16 + tr;
        ushort4 o;
        o.x = Ts[cc][tc4 + 0]; o.y = Ts[cc][tc4 + 1];
        o.z = Ts[cc][tc4 + 2]; o.w = Ts[cc][tc4 + 3];
        *(ushort4*)&out[(size_t)(c0 + cc) * R + r0 + tc4] = o;
    }
}

// ---------------------------------------------------------------------------
// Per-head V transpose (bf16): in [bh][s][64] -> out [bh][d=64][s=1024]
// ---------------------------------------------------------------------------
__global__ __launch_bounds__(256)
void vtransp_kernel(const USH* __restrict__ in, USH* __restrict__ out) {
    __shared__ USH T[64][72];
    const int bh = blockIdx.x >> 4;
    const int s0 = (blockIdx.x & 15) * 64;
    const int r = threadIdx.x >> 4;
    const int c4 = (threadIdx.x & 15) * 4;
    #pragma unroll
    for (int ph = 0; ph < 4; ++ph) {
        const int row = ph * 16 + r;   // s offset
        const ushort4 v = *(const ushort4*)
            &in[((size_t)bh * S_LEN + s0 + row) * DK + c4];
        T[row][c4 + 0] = v.x; T[row][c4 + 1] = v.y;
        T[row][c4 + 2] = v.z; T[row][c4 + 3] = v.w;
    }
    __syncthreads();
    #pragma unroll
    for (int ph = 0; ph < 4; ++ph) {
        const int d = ph * 16 + r;
        ushort4 o;
        o.x = T[c4 + 0][d]; o.y = T[c4 + 1][d];
        o.z = T[c4 + 2][d]; o.w = T[c4 + 3][d];
        *(ushort4*)&out[(size_t)bh * (S_LEN * DK) + (size_t)d * S_LEN + s0 + c4] = o;
    }
}

// ---------------------------------------------------------------------------
// bf16 MFMA GEMM (m97 structure) — q/k/v written bf16 when QKV=1,
// all row-major coalesced (V transposed by separate kernel).
// ---------------------------------------------------------------------------
template<int QKV>
__global__ __launch_bounds__(256)
void mfma_gemm_kernel(const USH* __restrict__ A, const USH* __restrict__ Bt,
                      const float* __restrict__ bias,
                      float* __restrict__ Cf, USH* __restrict__ Cq,
                      USH* __restrict__ Ck, USH* __restrict__ Cv,
                      int M, int N, int K) {
    __shared__ __align__(16) USH As[128 * 32];
    __shared__ __align__(16) USH Bs[128 * 32];
    const int t = threadIdx.x;
    const int w = t >> 6, lane = t & 63, g = lane >> 4, c = lane & 15;
    const int wm = w >> 1, wn = w & 1;
    const int bm0 = blockIdx.y * 128, bn0 = blockIdx.x * 128;

    const int sk = ((t & 3) ^ ((t >> 3) & 3)) * 8;
    const USH* pa0 = A + (size_t)(bm0 + (t >> 2)) * K + sk;
    const USH* pa1 = pa0 + (size_t)64 * K;
    const USH* pb0 = Bt + (size_t)(bn0 + (t >> 2)) * K + sk;
    const USH* pb1 = pb0 + (size_t)64 * K;
    USH* ldsA0 = &As[(t & ~63) * 8];
    USH* ldsA1 = ldsA0 + 2048;
    USH* ldsB0 = &Bs[(t & ~63) * 8];
    USH* ldsB1 = ldsB0 + 2048;

    unsigned aoff[4], boff[4];
    #pragma unroll
    for (int i = 0; i < 4; ++i) {
        const int r = wm * 64 + i * 16 + c;
        aoff[i] = ((unsigned)(r * 64 + g * 16)) ^ ((((unsigned)r >> 1) & 3) << 4);
        const int n = wn * 64 + i * 16 + c;
        boff[i] = ((unsigned)(n * 64 + g * 16)) ^ ((((unsigned)n >> 1) & 3) << 4);
    }

    f32x4 acc[4][4];
    #pragma unroll
    for (int i = 0; i < 4; ++i)
        #pragma unroll
        for (int j = 0; j < 4; ++j) acc[i][j] = (f32x4)0.f;

    for (int k0 = 0; k0 < K; k0 += 32) {
        gload16(pa0 + k0, ldsA0);
        gload16(pa1 + k0, ldsA1);
        gload16(pb0 + k0, ldsB0);
        gload16(pb1 + k0, ldsB1);
        __syncthreads();

        bf16x8 af[4], bfr[4];
        #pragma unroll
        for (int i = 0; i < 4; ++i) af[i] = *(const bf16x8*)((const char*)As + aoff[i]);
        #pragma unroll
        for (int j = 0; j < 4; ++j) bfr[j] = *(const bf16x8*)((const char*)Bs + boff[j]);
        #pragma unroll
        for (int i = 0; i < 4; ++i)
            #pragma unroll
            for (int j = 0; j < 4; ++j)
                acc[i][j] = __builtin_amdgcn_mfma_f32_16x16x32_bf16(
                    af[i], bfr[j], acc[i][j], 0, 0, 0);
        __syncthreads();
    }

    #pragma unroll
    for (int i = 0; i < 4; ++i) {
        #pragma unroll
        for (int reg = 0; reg < 4; ++reg) {
            const int m = bm0 + wm * 64 + i * 16 + g * 4 + reg;
            #pragma unroll
            for (int j = 0; j < 4; ++j) {
                const int n = bn0 + wn * 64 + j * 16 + c;
                const float v = acc[i][j][reg] + bias[n];
                if (QKV) {
                    const int which = n >> 10;
                    const int h = (n & 1023) >> 6, d = n & 63;
                    const int b = m >> 10, s = m & 1023;
                    const size_t idx = (((size_t)(b * NH + h)) * S_LEN + s) * DK + d;
                    if (which == 0)      Cq[idx] = (USH)f2b(v);
                    else if (which == 1) Ck[idx] = (USH)f2b(v);
                    else                 Cv[idx] = (USH)f2b(v);
                } else {
                    Cf[(size_t)m * N + n] = v;
                }
            }
        }
    }
}

// ---------------------------------------------------------------------------
// MFMA flash attention: 8 waves x 128 q-rows per block, KVBLK=64, dbuf async
// staging. Fixed-shift softmax; per-lane partial sums reduced in epilogue.
// LPT ordering: heavy blocks (large ib) dispatch FIRST (R10: −24 µs).
// ---------------------------------------------------------------------------
__global__ __launch_bounds__(512, 4)
void attn_mfma_kernel(const USH* __restrict__ qb,
                      const USH* __restrict__ kbuf,
                      const USH* __restrict__ vtg,
                      const float* __restrict__ lut_k,
                      const float* __restrict__ lut_v,
                      USH* __restrict__ ao) {
    const int bid = blockIdx.x;
    const int logical = (bid & 7) * 128 + (bid >> 3);   // XCD-contiguous bh
    const int ib = 7 - (logical & 7);                   // LPT: big ib first
    const int bh = logical >> 3;
    const int b = bh >> 4, h = bh & 15;
    const int i0 = ib * 128;
    const int t = threadIdx.x;
    const int w = t >> 6;          // 0..7
    const int lane = t & 63;
    const int g = lane >> 4;
    const int c = lane & 15;

    __shared__ __align__(16) char smem[64640];
    char* pb    = smem + 32768;              // P buffers (main loop)
    char* qsb   = smem + 32768;              // phase0 alias: q [128][64] swz
    char* lutkb = smem + 56448;              // phase0 alias of tapss
    USH* qrelb  = (USH*)(smem + 49152);      // [128][20] bf16
    USH* lvfb   = (USH*)(smem + 54272);      // [17][64] bf16
    float* tapss = (float*)(smem + 56448);   // [128][16] p values

    const USH* qp  = qb   + (size_t)bh * (S_LEN * DK);
    const USH* kp  = kbuf + (size_t)bh * (S_LEN * DK);
    const USH* vtp = vtg  + (size_t)bh * (S_LEN * DK);  // [d=64][s=1024]

    // async stage of one 64x64 K tile + V^T tile (512 thr = 1 gload16 each)
    auto stage = [&](int j0, int koff, int voff) {
        const int o = t * 16;
        const int row = o >> 7;
        const int chunk = (o >> 4) & 7;
        const int sc = (chunk ^ (row & 7)) * 8;
        gload16(kp + (size_t)(j0 + row) * DK + sc, smem + koff + o);
        gload16(vtp + (size_t)row * S_LEN + j0 + sc, smem + voff + o);
    };

    // ---- phase 0: issue tile-0 loads; stage q (bf16, swizzled) + LUTs ----
    stage(0, 0, 16384);
    for (int f = t; f < 2048; f += 512) {
        const int row = f >> 4, c4 = (f & 15) * 4;
        unsigned byte = ((unsigned)(row * 128 + c4 * 2)) ^ (((unsigned)row & 7) << 4);
        *(ushort4*)(qsb + byte) = *(const ushort4*)&qp[(size_t)(i0 + row) * DK + c4];
    }
    // lut_k -> bf16 LDS [32][64], rows 17..31 zero, swizzled
    for (int e = t; e < 32 * 64; e += 512) {
        const int row = e >> 6, d = e & 63;
        const USH v = (row < 17) ? (USH)f2b(lut_k[row * 64 + d]) : (USH)0;
        unsigned byte = ((unsigned)(row * 128 + d * 2)) ^ (((unsigned)row & 7) << 4);
        *(USH*)(lutkb + byte) = v;
    }
    for (int e = t; e < 17 * 64; e += 512)
        lvfb[e] = (USH)f2b(lut_v[e]);
    __syncthreads();   // drains tile-0 gloads too

    // Q fragments straight from swizzled bf16 LDS (wave w owns rows w*16..+15)
    bf16x8 qa[2];
    {
        const int row = w * 16 + c;
        #pragma unroll
        for (int kh = 0; kh < 2; ++kh) {
            unsigned byte = ((unsigned)(row * 128 + kh * 64 + g * 16))
                          ^ (((unsigned)row & 7) << 4);
            qa[kh] = *(const bf16x8*)(qsb + byte);
        }
    }

    // qrel via MFMA: lut_k rows as 17 virtual keys (2 col sub-tiles)
    {
        f32x4 qr[2];
        qr[0] = (f32x4)0.f; qr[1] = (f32x4)0.f;
        #pragma unroll
        for (int sub2 = 0; sub2 < 2; ++sub2) {
            const int tap = sub2 * 16 + c;
            #pragma unroll
            for (int kh = 0; kh < 2; ++kh) {
                unsigned byte = ((unsigned)(tap * 128 + kh * 64 + g * 16))
                              ^ (((unsigned)tap & 7) << 4);
                bf16x8 lb = *(const bf16x8*)(lutkb + byte);
                qr[sub2] = __builtin_amdgcn_mfma_f32_16x16x32_bf16(
                    qa[kh], lb, qr[sub2], 0, 0, 0);
            }
        }
        #pragma unroll
        for (int sub2 = 0; sub2 < 2; ++sub2) {
            const int tap = sub2 * 16 + c;
            if (tap < 17) {
                #pragma unroll
                for (int r = 0; r < 4; ++r)
                    qrelb[(w * 16 + g * 4 + r) * 20 + tap] = (USH)f2b(qr[sub2][r]);
            }
        }
    }
    __syncthreads();   // qsb/lutkb dead; qrelb ready; pb/tapss free

    // hoist tap-0 qrel (pre-scaled by EXPSCALE) for interior tiles
    float qrel0s[4];
    #pragma unroll
    for (int r = 0; r < 4; ++r)
        qrel0s[r] = b2f(qrelb[(w * 16 + g * 4 + r) * 20]) * EXPSCALE;

    f32x4 acc[4];
    #pragma unroll
    for (int dt = 0; dt < 4; ++dt) acc[dt] = (f32x4)0.f;
    float l_r[4];   // per-lane PARTIAL row sums (reduced in epilogue)
    #pragma unroll
    for (int r = 0; r < 4; ++r) l_r[r] = 0.f;

    const int NT = 2 * ib + 2;
    for (int tile = 0; tile < NT; ++tile) {
        const int cur = tile & 1;
        if (tile + 1 < NT)
            stage((tile + 1) << 6, cur ? 0 : 8192, cur ? 16384 : 24576);
        const char* ktb = smem + (cur ? 8192 : 0);
        const char* vtb = smem + (cur ? 24576 : 16384);

        // ---- QK^T ----
        float p[4][4];
        __builtin_amdgcn_s_setprio(1);
        f32x4 s[4];
        #pragma unroll
        for (int sub = 0; sub < 4; ++sub) {
            s[sub] = (f32x4)0.f;
            const int krow = sub * 16 + c;
            #pragma unroll
            for (int kh = 0; kh < 2; ++kh) {
                unsigned byte = ((unsigned)krow << 7) + ((unsigned)kh << 6) + ((unsigned)g << 4);
                byte ^= (unsigned)(krow & 7) << 4;
                bf16x8 kb = *(const bf16x8*)(ktb + byte);
                s[sub] = __builtin_amdgcn_mfma_f32_16x16x32_bf16(qa[kh], kb, s[sub], 0, 0, 0);
            }
        }
        __builtin_amdgcn_s_setprio(0);

        if (tile < NT - 3) {
            // ---- interior fast path: dj <= -65 -> tap index 0 everywhere ----
            #pragma unroll
            for (int sub = 0; sub < 4; ++sub)
                #pragma unroll
                for (int r = 0; r < 4; ++r)
                    p[sub][r] = fast_exp2(s[sub][r] * EXPSCALE + qrel0s[r]);
        } else {
            // ---- boundary: clamped tap lookup + causal mask + tap capture ----
            #pragma unroll
            for (int sub = 0; sub < 4; ++sub) {
                const int dbase = tile * 64 + (sub * 16 + c) - i0 - (w * 16 + g * 4);
                #pragma unroll
                for (int r = 0; r < 4; ++r) {
                    const int dj = dbase - r;
                    int t17 = dj + 16;
                    t17 = t17 < 0 ? 0 : (t17 > 16 ? 16 : t17);
                    const int il = w * 16 + g * 4 + r;
                    float pv = fast_exp2((s[sub][r] + b2f(qrelb[il * 20 + t17])) * EXPSCALE);
                    if (dj > 0) pv = 0.f;
                    p[sub][r] = pv;
                    if (dj >= -15 && dj <= 0)
                        tapss[il * 16 + dj + 15] = pv;
                }
            }
        }

        // ---- accumulate per-lane partial row sums (no cross-lane ops) ----
        #pragma unroll
        for (int r = 0; r < 4; ++r)
            l_r[r] += (p[0][r] + p[1][r]) + (p[2][r] + p[3][r]);

        // ---- P -> per-wave LDS (bf16, swizzled) ----
        char* pw = pb + w * 2048;
        #pragma unroll
        for (int sub = 0; sub < 4; ++sub)
            #pragma unroll
            for (int r = 0; r < 4; ++r) {
                const int row = g * 4 + r;
                unsigned byte = ((unsigned)row << 7) + (((unsigned)(sub * 16 + c)) << 1);
                byte ^= (unsigned)(row & 7) << 4;
                *(short*)(pw + byte) = f2b(p[sub][r]);
            }

        // ---- PV ----
        bf16x8 pa[2];
        #pragma unroll
        for (int jh = 0; jh < 2; ++jh) {
            unsigned byte = ((unsigned)c << 7) + ((unsigned)jh << 6) + ((unsigned)g << 4);
            byte ^= (unsigned)(c & 7) << 4;
            pa[jh] = *(const bf16x8*)(pw + byte);
        }
        __builtin_amdgcn_s_setprio(1);
        #pragma unroll
        for (int dt = 0; dt < 4; ++dt) {
            const int d = dt * 16 + c;
            #pragma unroll
            for (int jh = 0; jh < 2; ++jh) {
                unsigned byte = ((unsigned)d << 7) + ((unsigned)jh << 6) + ((unsigned)g << 4);
                byte ^= (unsigned)(d & 7) << 4;
                bf16x8 vb = *(const bf16x8*)(vtb + byte);
                acc[dt] = __builtin_amdgcn_mfma_f32_16x16x32_bf16(pa[jh], vb, acc[dt], 0, 0, 0);
            }
        }
        __builtin_amdgcn_s_setprio(0);
        __syncthreads();
    }

    // ---- epilogue: reduce row sums, taps + bin-0 residual, write ----
    const int rbase = w * 16 + g * 4;
    #pragma unroll
    for (int r = 0; r < 4; ++r) {
        float lsum = l_r[r];
        #pragma unroll
        for (int msk = 1; msk < 16; msk <<= 1)
            lsum += __shfl_xor(lsum, msk);
        const int il = rbase + r;
        float c0 = lsum;
        float tp[16];
        #pragma unroll
        for (int tap = 0; tap < 16; ++tap) {
            const int jg = i0 + il + tap - 15;
            const float pv = (jg >= 0) ? tapss[il * 16 + tap] : 0.f;
            tp[tap] = pv;
            c0 -= pv;
        }
        const float invl = 1.f / lsum;
        #pragma unroll
        for (int dt = 0; dt < 4; ++dt) {
            const int d = dt * 16 + c;
            float o = acc[dt][r] + c0 * b2f(lvfb[d]);
            #pragma unroll
            for (int tap = 0; tap < 16; ++tap)
                o += tp[tap] * b2f(lvfb[(tap + 1) * 64 + d]);
            o *= invl;
            ao[((size_t)b * S_LEN + (i0 + il)) * D_MODEL + h * DK + d] = (USH)f2b(o);
        }
    }
}

// ---------------------------------------------------------------------------
extern "C" void kernel_launch(void* const* d_in, const int* in_sizes, int n_in,
                              void* d_out, int out_size, void* d_ws, size_t ws_size,
                              hipStream_t stream) {
    const float* x      = (const float*)d_in[0];
    const float* W_attn = (const float*)d_in[1];
    const float* b_attn = (const float*)d_in[2];
    const float* W_proj = (const float*)d_in[3];
    const float* b_proj = (const float*)d_in[4];
    const float* lut_k  = (const float*)d_in[5];
    const float* lut_v  = (const float*)d_in[6];
    float* out = (float*)d_out;

    // workspace layout (all USH)
    USH* qb    = (USH*)d_ws;            // 8M
    USH* kb    = qb + HSZ;              // 8M
    USH* vb    = kb + HSZ;              // 8M (row-major V)
    USH* vtg   = vb + HSZ;              // 8M (per-head transposed V)
    USH* aob   = vtg + HSZ;             // 8M
    USH* xb    = aob + HSZ;             // 8M
    USH* watt  = xb + HSZ;              // 3M
    USH* wproj = watt + 3145728;        // 1M

    // 0) conversions
    conv_bf16_kernel<<<HSZ / (256 * 8), 256, 0, stream>>>(x, xb);
    transp_bf16_kernel<<<dim3(3072 / 64, 1024 / 64), 256, 0, stream>>>(
        W_attn, watt, 1024, 3072);
    transp_bf16_kernel<<<dim3(1024 / 64, 1024 / 64), 256, 0, stream>>>(
        W_proj, wproj, 1024, 1024);

    // 1) QKV projection (bf16 MFMA), coalesced row-major outputs
    mfma_gemm_kernel<1><<<dim3(3072 / 128, 8192 / 128), 256, 0, stream>>>(
        xb, watt, b_attn, nullptr, qb, kb, vb, 8192, 3072, 1024);

    // 1b) per-head V transpose (coalesced LDS-tile kernel, ~6 us)
    vtransp_kernel<<<2048, 256, 0, stream>>>(vb, vtg);

    // 2) attention (8 waves x 128 q-rows per block, LPT ordering)
    attn_mfma_kernel<<<1024, 512, 0, stream>>>(qb, kb, vtg, lut_k, lut_v, aob);

    // 3) output projection (bf16 MFMA)
    mfma_gemm_kernel<0><<<dim3(1024 / 128, 8192 / 128), 256, 0, stream>>>(
        aob, wproj, b_proj, out, nullptr, nullptr, nullptr, 8192, 1024, 1024);
}